// Round 10
// baseline (198.458 us; speedup 1.0000x reference)
//
#include <hip/hip_runtime.h>
#include <hip/hip_bf16.h>
#include <math.h>

// Problem constants (fixed by the harness)
#define BB 4
#define SEQ 2048
#define DIM 512
#define NH 8
#define HD 64

typedef __attribute__((ext_vector_type(8))) short short8;
typedef __attribute__((ext_vector_type(4))) float f32x4;
typedef __attribute__((ext_vector_type(2))) unsigned int u32x2;
typedef __attribute__((address_space(3))) const ushort lds_cushort;

static __device__ inline ushort f2bf(float f) {
    __hip_bfloat16 h = __float2bfloat16(f);
    union { __hip_bfloat16 h; ushort u; } cv;
    cv.h = h;
    return cv.u;
}
static __device__ inline float bf2f(ushort u) {
    return __uint_as_float((uint)u << 16);
}

#define GLOAD16(g, l)                                                          \
    __builtin_amdgcn_global_load_lds(                                          \
        (const __attribute__((address_space(1))) uint32_t*)(g),                \
        (__attribute__((address_space(3))) uint32_t*)(l), 16, 0, 0)

// hardware transpose read: 4 bf16 at 16-element (32B) stride from lane's address
static __device__ __forceinline__ u32x2 tr16_b64(lds_cushort* p) {
    u32x2 r;
    asm volatile("ds_read_b64_tr_b16 %0, %1" : "=v"(r) : "v"(p) : "memory");
    return r;
}

// ---------------- Kernel A: x_bf = bf16(inputs + sine positional encoding) --------
__global__ __launch_bounds__(256) void pos_add_bf16_kernel(const float* __restrict__ in,
                                                           ushort* __restrict__ xbf) {
    int idx = blockIdx.x * 256 + threadIdx.x;      // 2097152 pairs
    int p = idx & 255;
    int n = (idx >> 8) & 2047;
    float e = (float)(2 * p) * (1.0f / 512.0f);
    float ts = __expf(-6.907755278982137f * e);    // (1/1000)^e
    float arev = (float)n * (ts * 0.15915494309189535f);   // angle in revolutions
    float f = arev - floorf(arev);
    float s = __builtin_amdgcn_sinf(f);            // sin(2*pi*f)
    float c = __builtin_amdgcn_cosf(f);
    float2 v = *(const float2*)(in + (size_t)idx * 2);
    uint pack = (uint)f2bf(v.x + s) | ((uint)f2bf(v.y + c) << 16);
    ((uint*)xbf)[idx] = pack;
}

// ---------------- Kernel A2: weight prep (wconv + wout merged) --------------------
__global__ __launch_bounds__(256) void wprep_kernel(const float* __restrict__ w,
                                                    ushort* __restrict__ wt,
                                                    const float* __restrict__ wo,
                                                    ushort* __restrict__ wobf) {
    int bid = blockIdx.x;
    int t = threadIdx.x;
    if (bid < 96) {
        __shared__ float tile[64][129];
        int ib = bid & 7;    // 0..7   (i blocks of 64)
        int jb = bid >> 3;   // 0..11  (col blocks of 128)
        #pragma unroll
        for (int u = 0; u < 8; ++u) {
            int idx = u * 1024 + t * 4;
            int r = idx >> 7, j = idx & 127;
            float4 v = *(const float4*)(w + (size_t)(ib * 64 + r) * 1536 + jb * 128 + j);
            tile[r][j] = v.x; tile[r][j + 1] = v.y; tile[r][j + 2] = v.z; tile[r][j + 3] = v.w;
        }
        __syncthreads();
        int j = t >> 1;
        int rh = (t & 1) * 32;
        int jg = jb * 128 + j;                 // = h*192 + o*3 + c
        int h = jg / 192;
        int rem = jg - h * 192;
        int o = rem / 3;
        int c = rem - o * 3;
        int nrow = c * 512 + h * 64 + o;
        #pragma unroll
        for (int s8 = 0; s8 < 4; ++s8) {
            short8 pk;
            #pragma unroll
            for (int q = 0; q < 8; ++q) pk[q] = (short)f2bf(tile[rh + s8 * 8 + q][j]);
            *(short8*)(wt + (size_t)nrow * 512 + ib * 64 + rh + s8 * 8) = pk;
        }
    } else {
        int g = (bid - 96) * 256 + t;   // 32768 dst elems
        int o2 = g >> 9, k = g & 511;
        int h = k >> 6, i = k & 63;
        wobf[g] = f2bf(wo[(size_t)i * 512 + h * 64 + o2]);
    }
}

// ---------------- Kernel B: QKV GEMM via bf16 MFMA, BK=64, XOR-swizzled LDS -------
__global__ __launch_bounds__(256) void qkv_mfma_kernel(const ushort* __restrict__ xbf,
                                                       const ushort* __restrict__ wt,
                                                       ushort* __restrict__ kbf,
                                                       ushort* __restrict__ vbf,
                                                       ushort* __restrict__ qbf) {
    __shared__ __align__(16) ushort As[128 * 64];
    __shared__ __align__(16) ushort Bs[128 * 64];
    int t = threadIdx.x;
    int w = t >> 6, lane = t & 63, l15 = lane & 15, lg = lane >> 4;
    int wr = w >> 1, wc = w & 1;
    int m0 = blockIdx.x * 128;
    int by = blockIdx.y;
    int n0 = by * 128;
    int sw = l15 & 7;
    f32x4 acc[4][4] = {};

    int rowp[4], colp[4];
    #pragma unroll
    for (int p = 0; p < 4; ++p) {
        int ch = t + 256 * p;
        rowp[p] = ch >> 3;
        colp[p] = (((ch & 7) ^ (rowp[p] & 7))) * 8;
    }

    for (int k0 = 0; k0 < 512; k0 += 64) {
        __syncthreads();
        #pragma unroll
        for (int p = 0; p < 4; ++p)
            GLOAD16(xbf + (size_t)(m0 + rowp[p]) * 512 + k0 + colp[p], As + (t + 256 * p) * 8);
        #pragma unroll
        for (int p = 0; p < 4; ++p)
            GLOAD16(wt + (size_t)(n0 + rowp[p]) * 512 + k0 + colp[p], Bs + (t + 256 * p) * 8);
        __syncthreads();
        #pragma unroll
        for (int ks = 0; ks < 2; ++ks) {
            short8 af[4], bf[4];
            #pragma unroll
            for (int mi = 0; mi < 4; ++mi)
                af[mi] = *(const short8*)&As[(wr * 64 + mi * 16 + l15) * 64 + ((ks * 4 + lg) ^ sw) * 8];
            #pragma unroll
            for (int ni = 0; ni < 4; ++ni)
                bf[ni] = *(const short8*)&Bs[(wc * 64 + ni * 16 + l15) * 64 + ((ks * 4 + lg) ^ sw) * 8];
            #pragma unroll
            for (int mi = 0; mi < 4; ++mi)
                #pragma unroll
                for (int ni = 0; ni < 4; ++ni)
                    acc[mi][ni] = __builtin_amdgcn_mfma_f32_16x16x32_bf16(af[mi], bf[ni], acc[mi][ni], 0, 0, 0);
        }
    }

    ushort* dst = (by < 4) ? kbf : (by < 8) ? vbf : qbf;
    int ho0 = (by & 3) * 128 + wc * 64;
    int mb = m0 + wr * 64;
    #pragma unroll
    for (int mi = 0; mi < 4; ++mi)
        #pragma unroll
        for (int ni = 0; ni < 4; ++ni)
            #pragma unroll
            for (int r = 0; r < 4; ++r)
                dst[(size_t)(mb + mi * 16 + lg * 4 + r) * 512 + ho0 + ni * 16 + l15] =
                    f2bf(acc[mi][ni][r]);
}

// ---------------- Kernel C: A_mem via bf16 MFMA (den fused as B-row 64) -----------
__global__ __launch_bounds__(256) void amem_mfma_kernel(const ushort* __restrict__ qbf,
                                                        const float* __restrict__ mem,
                                                        const float* __restrict__ zin,
                                                        ushort* __restrict__ ambf) {
    int bid = blockIdx.x;               // 4*8*8 = 256
    int nt = bid & 7;
    int h = (bid >> 3) & 7;
    int b = bid >> 6;
    __shared__ __align__(16) ushort bt_s[80 * 64];
    int t = threadIdx.x;
    int w = t >> 6, lane = t & 63, l15 = lane & 15, lg = lane >> 4;

    {
        int d = t >> 2;
        int o0 = (t & 3) * 16;
        const float* msrc = mem + (size_t)(b * 8 + h) * 4096 + (size_t)d * 64 + o0;
        #pragma unroll
        for (int j = 0; j < 16; ++j) {
            int o = o0 + j;
            int c = (d >> 3) ^ (o & 7);
            bt_s[(o * 8 + c) * 8 + (d & 7)] = f2bf(msrc[j]);
        }
        if (t < 64) {
            bt_s[(64 * 8 + (t >> 3)) * 8 + (t & 7)] = f2bf(zin[(b * 8 + h) * 64 + t]);
        }
    }
    __syncthreads();

    int sw = l15 & 7;
    short8 bfr[5][2];
    #pragma unroll
    for (int n = 0; n < 5; ++n) {
        const ushort* br = &bt_s[(n * 16 + l15) * 64];
        bfr[n][0] = *(const short8*)&br[(lg ^ sw) * 8];
        bfr[n][1] = *(const short8*)&br[((4 + lg) ^ sw) * 8];
    }

    int rowbase = b * 2048 + nt * 256 + w * 64;
    f32x4 acc[4][5] = {};
    #pragma unroll
    for (int m = 0; m < 4; ++m) {
        const ushort* qrow = qbf + (size_t)(rowbase + m * 16 + l15) * 512 + h * 64;
        short8 q0 = *(const short8*)(qrow + lg * 8);
        short8 q1 = *(const short8*)(qrow + 32 + lg * 8);
        short8 a0, a1;
        #pragma unroll
        for (int j = 0; j < 8; ++j) {
            float f0 = bf2f((ushort)q0[j]);
            float f1 = bf2f((ushort)q1[j]);
            a0[j] = (short)f2bf(f0 > 0.f ? f0 + 1.f : __expf(f0));
            a1[j] = (short)f2bf(f1 > 0.f ? f1 + 1.f : __expf(f1));
        }
        #pragma unroll
        for (int n = 0; n < 5; ++n) {
            acc[m][n] = __builtin_amdgcn_mfma_f32_16x16x32_bf16(a0, bfr[n][0], acc[m][n], 0, 0, 0);
            acc[m][n] = __builtin_amdgcn_mfma_f32_16x16x32_bf16(a1, bfr[n][1], acc[m][n], 0, 0, 0);
        }
    }

    #pragma unroll
    for (int m = 0; m < 4; ++m) {
        float inv[4];
        #pragma unroll
        for (int r = 0; r < 4; ++r) {
            float d = __shfl(acc[m][4][r], (lane & 48));   // den from l15==0 lane
            inv[r] = 1.f / (d + 1e-8f);
        }
        #pragma unroll
        for (int r = 0; r < 4; ++r) {
            ushort* dst = ambf + (size_t)(rowbase + m * 16 + lg * 4 + r) * 512 + h * 64;
            #pragma unroll
            for (int n = 0; n < 4; ++n)
                dst[n * 16 + l15] = f2bf(acc[m][n][r] * inv[r]);
        }
    }
}

// ---------------- Kernel D1: delta partials (256 blocks) --------------------------
__global__ __launch_bounds__(256) void delta_part_kernel(const ushort* __restrict__ kbf,
                                                         const ushort* __restrict__ vbf,
                                                         const ushort* __restrict__ ambf,
                                                         float* __restrict__ part,
                                                         float* __restrict__ zpart) {
    int bid = blockIdx.x;      // chunk*32 + bh
    int bh = bid & 31;
    int chunk = bid >> 5;
    int h = bh & 7, b = bh >> 3;
    __shared__ __align__(16) float ke_s[2048];   // [32][64]
    __shared__ __align__(16) float vm_s[2048];
    int t = threadIdx.x;
    int tx = t & 15, ty = t >> 4;
    float acc[4][4] = {};
    float nz = 0.f;
    int nbase = chunk * 256;
    for (int n0 = 0; n0 < 256; n0 += 32) {
        {
            int nn = t >> 3, cc = (t & 7) * 8;
            size_t g = (size_t)(b * 2048 + nbase + n0 + nn) * 512 + h * 64 + cc;
            short8 k8 = *(const short8*)(kbf + g);
            short8 v8 = *(const short8*)(vbf + g);
            short8 a8 = *(const short8*)(ambf + g);
            #pragma unroll
            for (int j = 0; j < 8; ++j) {
                float kv = bf2f((ushort)k8[j]);
                ke_s[t * 8 + j] = kv > 0.f ? kv + 1.f : __expf(kv);
                vm_s[t * 8 + j] = bf2f((ushort)v8[j]) - bf2f((ushort)a8[j]);
            }
        }
        __syncthreads();
        #pragma unroll
        for (int nn = 0; nn < 32; ++nn) {
            float4 ka4 = *(const float4*)&ke_s[nn * 64 + ty * 4];
            float4 vv4 = *(const float4*)&vm_s[nn * 64 + tx * 4];
            float ka[4] = {ka4.x, ka4.y, ka4.z, ka4.w};
            float vv[4] = {vv4.x, vv4.y, vv4.z, vv4.w};
            #pragma unroll
            for (int i = 0; i < 4; ++i)
                #pragma unroll
                for (int j = 0; j < 4; ++j) acc[i][j] += ka[i] * vv[j];
        }
        if (t < 64) {
            #pragma unroll
            for (int nn = 0; nn < 32; ++nn) nz += ke_s[nn * 64 + t];
        }
        __syncthreads();
    }
    float* pdst = part + (size_t)bid * 4096;
    #pragma unroll
    for (int i = 0; i < 4; ++i)
        #pragma unroll
        for (int j = 0; j < 4; ++j)
            pdst[(ty * 4 + i) * 64 + tx * 4 + j] = acc[i][j];
    if (t < 64) zpart[bid * 64 + t] = nz;
}

// ---------------- Kernel D2: delta reduce -----------------------------------------
__global__ __launch_bounds__(256) void delta_reduce_kernel(const float* __restrict__ part,
                                                           const float* __restrict__ zpart,
                                                           const float* __restrict__ mem,
                                                           const float* __restrict__ zin,
                                                           float* __restrict__ out_mem,
                                                           float* __restrict__ out_z) {
    int bh = blockIdx.x;
    int t = threadIdx.x;
    #pragma unroll
    for (int q = 0; q < 4; ++q) {
        int e = t * 16 + q * 4;
        float4 acc = *(const float4*)(mem + (size_t)bh * 4096 + e);
        #pragma unroll
        for (int c = 0; c < 8; ++c) {
            float4 pv = *(const float4*)(part + (size_t)(c * 32 + bh) * 4096 + e);
            acc.x += pv.x; acc.y += pv.y; acc.z += pv.z; acc.w += pv.w;
        }
        *(float4*)(out_mem + (size_t)bh * 4096 + e) = acc;
    }
    if (t < 64) {
        float z = zin[bh * 64 + t];
        #pragma unroll
        for (int c = 0; c < 8; ++c) z += zpart[(c * 32 + bh) * 64 + t];
        out_z[bh * 64 + t] = z;
    }
}

// ---------------- Kernel E: flash, kt-split halves for balance + occupancy --------
// O,l are pure sums (no-max softmax) -> kt-range splits combine linearly.
// half0: kt 0..15, tile A complete (rA<=15) + tile B partial. half1: kt 16..rB, B partial.
__global__ __launch_bounds__(256, 2) void flash6_kernel(const ushort* __restrict__ qbf,
                                                        const ushort* __restrict__ kbf,
                                                        const ushort* __restrict__ vbf,
                                                        ushort* __restrict__ adbf,
                                                        float* __restrict__ pO,
                                                        float* __restrict__ pl) {
    int bid0 = blockIdx.x;
    int bid = (bid0 & 7) * 128 + (bid0 >> 3);      // 1024 % 8 == 0: bijective XCD remap
    int half = bid >> 9;
    int rem = bid & 511;
    int i = rem & 15;
    int h = (rem >> 4) & 7;
    int b = rem >> 7;
    __shared__ __align__(16) ushort k_s[2][4096];  // [key 64][d 64], chunk-XOR swz
    __shared__ __align__(16) ushort v_s[2][4096];  // [dblk 4][n 64][d' 16], linear
    __shared__ __align__(16) ushort p_s[4][1024];  // per-wave P^T [k 64][q 16]
    int t = threadIdx.x;
    int w = t >> 6, lane = t & 63, l15 = lane & 15, lg = lane >> 4;
    const int rA = i, rB = 31 - i;
    const int sw = l15 & 7;
    const float C = 0.06375875f;   // (1/sqrt(512)) * log2(e)
    int kt0 = half ? 16 : 0;
    int kt1 = half ? rB : 15;

    const ushort* qbase = qbf + (size_t)(b * 2048) * 512 + h * 64 + lg * 8;
    short8 qfA[2], qfB[2];
    #pragma unroll
    for (int c = 0; c < 2; ++c) {
        short8 rb = *(const short8*)(qbase + (size_t)(rB * 64 + w * 16 + l15) * 512 + c * 32);
        #pragma unroll
        for (int j = 0; j < 8; ++j) qfB[c][j] = (short)f2bf(bf2f((ushort)rb[j]) * C);
    }
    if (!half) {
        #pragma unroll
        for (int c = 0; c < 2; ++c) {
            short8 ra = *(const short8*)(qbase + (size_t)(rA * 64 + w * 16 + l15) * 512 + c * 32);
            #pragma unroll
            for (int j = 0; j < 8; ++j) qfA[c][j] = (short)f2bf(bf2f((ushort)ra[j]) * C);
        }
    }
    f32x4 oA[4] = {}, oB[4] = {};
    f32x4 lA = {0.f, 0.f, 0.f, 0.f}, lB = {0.f, 0.f, 0.f, 0.f};

    int ch0 = t, ch1 = t + 256;
    int krow0 = ch0 >> 3, ksc0 = (ch0 & 7) ^ (krow0 & 7);
    int krow1 = ch1 >> 3, ksc1 = (ch1 & 7) ^ (krow1 & 7);
    int vd0 = ch0 >> 7, vn0 = (ch0 >> 1) & 63, vh0 = ch0 & 1;
    int vd1 = ch1 >> 7, vn1 = (ch1 >> 1) & 63, vh1 = ch1 & 1;
    const ushort* kbase = kbf + (size_t)(b * 2048) * 512 + h * 64;
    const ushort* vbase = vbf + (size_t)(b * 2048) * 512 + h * 64;
    ushort* pw = &p_s[w][0];

    short8 ones;
    #pragma unroll
    for (int j = 0; j < 8; ++j) ones[j] = (short)0x3F80;   // bf16 1.0

    short8 kf[4][2], vf[4][2];

    auto STAGE = [&](int buf, int kt) {
        GLOAD16(kbase + (size_t)(kt * 64 + krow0) * 512 + ksc0 * 8, &k_s[buf][ch0 * 8]);
        GLOAD16(kbase + (size_t)(kt * 64 + krow1) * 512 + ksc1 * 8, &k_s[buf][ch1 * 8]);
        GLOAD16(vbase + (size_t)(kt * 64 + vn0) * 512 + vd0 * 16 + vh0 * 8, &v_s[buf][ch0 * 8]);
        GLOAD16(vbase + (size_t)(kt * 64 + vn1) * 512 + vd1 * 16 + vh1 * 8, &v_s[buf][ch1 * 8]);
    };

    auto proc = [&](const short8* qf, f32x4* oo, f32x4& ll, int rt, int kt) {
        f32x4 s[4];
        #pragma unroll
        for (int t4 = 0; t4 < 4; ++t4) {
            f32x4 z = {0.f, 0.f, 0.f, 0.f};
            z = __builtin_amdgcn_mfma_f32_16x16x32_bf16(qf[0], kf[t4][0], z, 0, 0, 0);
            z = __builtin_amdgcn_mfma_f32_16x16x32_bf16(qf[1], kf[t4][1], z, 0, 0, 0);
            s[t4] = z;
        }
        if (kt == rt) {
            #pragma unroll
            for (int t4 = 0; t4 < 4; ++t4) {
                int colb = t4 * 16 + l15;
                int rowb = w * 16 + lg * 4;
                #pragma unroll
                for (int r = 0; r < 4; ++r)
                    if (colb > rowb + r) s[t4][r] = -1e30f;
            }
        }
        #pragma unroll
        for (int t4 = 0; t4 < 4; ++t4) {
            union { ushort u[4]; u32x2 d; } pk;
            #pragma unroll
            for (int r = 0; r < 4; ++r)
                pk.u[r] = f2bf(__builtin_amdgcn_exp2f(s[t4][r]));
            *(u32x2*)&pw[(t4 * 16 + l15) * 16 + lg * 4] = pk.d;
        }
        u32x2 praw0, praw1, praw2, praw3;
        {
            lds_cushort* pb = (lds_cushort*)&pw[l15];
            praw0 = tr16_b64(pb + (lg * 8 + 0) * 16);
            praw1 = tr16_b64(pb + (lg * 8 + 4) * 16);
            praw2 = tr16_b64(pb + (32 + lg * 8 + 0) * 16);
            praw3 = tr16_b64(pb + (32 + lg * 8 + 4) * 16);
        }
        asm volatile("s_waitcnt lgkmcnt(0)" ::: "memory");
        __builtin_amdgcn_sched_barrier(0);
        union { u32x2 d[2]; short8 s8; } up0, up1;
        up0.d[0] = praw0; up0.d[1] = praw1;
        up1.d[0] = praw2; up1.d[1] = praw3;
        short8 pf0 = up0.s8, pf1 = up1.s8;
        ll = __builtin_amdgcn_mfma_f32_16x16x32_bf16(pf0, ones, ll, 0, 0, 0);
        ll = __builtin_amdgcn_mfma_f32_16x16x32_bf16(pf1, ones, ll, 0, 0, 0);
        #pragma unroll
        for (int dt = 0; dt < 4; ++dt) {
            oo[dt] = __builtin_amdgcn_mfma_f32_16x16x32_bf16(pf0, vf[dt][0], oo[dt], 0, 0, 0);
            oo[dt] = __builtin_amdgcn_mfma_f32_16x16x32_bf16(pf1, vf[dt][1], oo[dt], 0, 0, 0);
        }
    };

    STAGE(0, kt0);
    for (int kt = kt0; kt <= kt1; ++kt) {
        int cur = (kt - kt0) & 1;
        __builtin_amdgcn_s_barrier();
        if (kt < kt1) {
            STAGE(cur ^ 1, kt + 1);
            asm volatile("s_waitcnt vmcnt(4)" ::: "memory");
        } else {
            asm volatile("s_waitcnt vmcnt(0)" ::: "memory");
        }
        __builtin_amdgcn_s_barrier();
        #pragma unroll
        for (int t4 = 0; t4 < 4; ++t4) {
            const ushort* kr = &k_s[cur][(t4 * 16 + l15) * 64];
            kf[t4][0] = *(const short8*)&kr[(lg ^ sw) * 8];
            kf[t4][1] = *(const short8*)&kr[((4 + lg) ^ sw) * 8];
        }
        u32x2 vraw[4][4];
        #pragma unroll
        for (int dt = 0; dt < 4; ++dt) {
            lds_cushort* vb = (lds_cushort*)&v_s[cur][dt * 1024 + l15];
            vraw[dt][0] = tr16_b64(vb + (lg * 8 + 0) * 16);
            vraw[dt][1] = tr16_b64(vb + (lg * 8 + 4) * 16);
            vraw[dt][2] = tr16_b64(vb + (32 + lg * 8 + 0) * 16);
            vraw[dt][3] = tr16_b64(vb + (32 + lg * 8 + 4) * 16);
        }
        asm volatile("s_waitcnt lgkmcnt(0)" ::: "memory");
        __builtin_amdgcn_sched_barrier(0);
        #pragma unroll
        for (int dt = 0; dt < 4; ++dt) {
            union { u32x2 d[2]; short8 s8; } u0, u1;
            u0.d[0] = vraw[dt][0]; u0.d[1] = vraw[dt][1];
            u1.d[0] = vraw[dt][2]; u1.d[1] = vraw[dt][3];
            vf[dt][0] = u0.s8;
            vf[dt][1] = u1.s8;
        }
        proc(qfB, oB, lB, rB, kt);
        if (!half && kt <= rA) proc(qfA, oA, lA, rA, kt);
    }

    if (!half) {
        // tile A is complete: normalize + final write
        #pragma unroll
        for (int r = 0; r < 4; ++r) {
            float inv = 1.f / lA[r];
            ushort* dst = adbf + (size_t)(b * 2048 + rA * 64 + w * 16 + lg * 4 + r) * 512 + h * 64;
            #pragma unroll
            for (int dt = 0; dt < 4; ++dt)
                dst[dt * 16 + l15] = f2bf(oA[dt][r] * inv);
        }
    }
    // tile B partial write (f32)
    {
        int slot = rem * 2 + half;
        float* od = pO + (size_t)slot * 4096;
        #pragma unroll
        for (int dt = 0; dt < 4; ++dt)
            #pragma unroll
            for (int r = 0; r < 4; ++r)
                od[(w * 16 + lg * 4 + r) * 64 + dt * 16 + l15] = oB[dt][r];
        if (l15 == 0) {
            #pragma unroll
            for (int r = 0; r < 4; ++r)
                pl[slot * 64 + w * 16 + lg * 4 + r] = lB[r];
        }
    }
}

// ---------------- Kernel E2: combine B-tile halves, normalize, write bf16 ---------
__global__ __launch_bounds__(256) void flash_combine_kernel(const float* __restrict__ pO,
                                                            const float* __restrict__ pl,
                                                            ushort* __restrict__ adbf) {
    int rem = blockIdx.x;        // 512: (b,h,i)
    int i = rem & 15;
    int h = (rem >> 4) & 7;
    int b = rem >> 7;
    int rB = 31 - i;
    int t = threadIdx.x;
    int r = t >> 2, c0 = (t & 3) * 16;
    size_t s0 = (size_t)(rem * 2) * 4096, s1 = s0 + 4096;
    float l = pl[(rem * 2) * 64 + r] + pl[(rem * 2 + 1) * 64 + r];
    float inv = 1.f / l;
    ushort* dst = adbf + (size_t)(b * 2048 + rB * 64 + r) * 512 + h * 64 + c0;
    short8 pk0, pk1;
    #pragma unroll
    for (int j = 0; j < 2; ++j) {
        float4 a = *(const float4*)(pO + s0 + r * 64 + c0 + j * 4);
        float4 bq = *(const float4*)(pO + s1 + r * 64 + c0 + j * 4);
        pk0[j * 4 + 0] = (short)f2bf((a.x + bq.x) * inv);
        pk0[j * 4 + 1] = (short)f2bf((a.y + bq.y) * inv);
        pk0[j * 4 + 2] = (short)f2bf((a.z + bq.z) * inv);
        pk0[j * 4 + 3] = (short)f2bf((a.w + bq.w) * inv);
    }
    #pragma unroll
    for (int j = 0; j < 2; ++j) {
        float4 a = *(const float4*)(pO + s0 + r * 64 + c0 + 8 + j * 4);
        float4 bq = *(const float4*)(pO + s1 + r * 64 + c0 + 8 + j * 4);
        pk1[j * 4 + 0] = (short)f2bf((a.x + bq.x) * inv);
        pk1[j * 4 + 1] = (short)f2bf((a.y + bq.y) * inv);
        pk1[j * 4 + 2] = (short)f2bf((a.z + bq.z) * inv);
        pk1[j * 4 + 3] = (short)f2bf((a.w + bq.w) * inv);
    }
    *(short8*)dst = pk0;
    *(short8*)(dst + 8) = pk1;
}

// ---------------- Kernel F: gated mix + output projection, 256 blocks -------------
__global__ __launch_bounds__(256) void outproj_mfma_kernel(const ushort* __restrict__ ambf,
                                                           const ushort* __restrict__ adbf,
                                                           const ushort* __restrict__ wobf,
                                                           const float* __restrict__ beta,
                                                           float* __restrict__ out) {
    __shared__ __align__(16) ushort W_s[64 * 512];   // 64KB, row o2, swizzled chunks
    __shared__ __align__(16) ushort A_s[32 * 64];    // 4KB, row m, swizzled chunks
    int t = threadIdx.x;
    int w = t >> 6, lane = t & 63, l15 = lane & 15, lg = lane >> 4;
    int msub = w & 1, nh = w >> 1;
    int m0 = blockIdx.x * 32;
    float g = 1.f / (1.f + __expf(-beta[0]));
    float gi = 1.f - g;

    #pragma unroll
    for (int p = 0; p < 16; ++p) {
        int ch = p * 256 + t;
        int row = ch >> 6, c = ch & 63;
        int cs = c ^ (row & 7);
        GLOAD16(wobf + (size_t)row * 512 + cs * 8, W_s + ch * 8);
    }

    int ar = t >> 3, ac = t & 7;   // 32 rows x 8 chunks
    int sw = l15 & 7;
    f32x4 acc[2] = {};

    for (int ks = 0; ks < 8; ++ks) {
        size_t gofs = (size_t)(m0 + ar) * 512 + ks * 64 + ac * 8;
        short8 a8 = *(const short8*)(ambf + gofs);
        short8 d8 = *(const short8*)(adbf + gofs);
        short8 x0;
        #pragma unroll
        for (int j = 0; j < 8; ++j)
            x0[j] = (short)f2bf(g * bf2f((ushort)a8[j]) + gi * bf2f((ushort)d8[j]));
        if (ks) __syncthreads();
        *(short8*)&A_s[(ar * 8 + (ac ^ (ar & 7))) * 8] = x0;
        __syncthreads();

        const ushort* arow = &A_s[(msub * 16 + l15) * 64];
        short8 af0 = *(const short8*)&arow[(lg ^ sw) * 8];
        short8 af1 = *(const short8*)&arow[((4 + lg) ^ sw) * 8];
        #pragma unroll
        for (int ni = 0; ni < 2; ++ni) {
            const ushort* wrow = &W_s[(nh * 32 + ni * 16 + l15) * 512];
            short8 bf0 = *(const short8*)&wrow[(ks * 8 + (lg ^ sw)) * 8];
            short8 bf1 = *(const short8*)&wrow[(ks * 8 + ((4 + lg) ^ sw)) * 8];
            acc[ni] = __builtin_amdgcn_mfma_f32_16x16x32_bf16(af0, bf0, acc[ni], 0, 0, 0);
            acc[ni] = __builtin_amdgcn_mfma_f32_16x16x32_bf16(af1, bf1, acc[ni], 0, 0, 0);
        }
    }

    #pragma unroll
    for (int ni = 0; ni < 2; ++ni)
        #pragma unroll
        for (int r = 0; r < 4; ++r)
            out[(size_t)(m0 + msub * 16 + lg * 4 + r) * 64 + nh * 32 + ni * 16 + l15] = acc[ni][r];
}

// ---------------- launcher --------------------------------------------------------
extern "C" void kernel_launch(void* const* d_in, const int* in_sizes, int n_in,
                              void* d_out, int out_size, void* d_ws, size_t ws_size,
                              hipStream_t stream) {
    const float* inputs = (const float*)d_in[0];
    const float* mem    = (const float*)d_in[1];
    const float* zin    = (const float*)d_in[2];
    const float* attnk  = (const float*)d_in[3];
    const float* outk   = (const float*)d_in[4];
    const float* beta   = (const float*)d_in[5];
    float* out = (float*)d_out;
    float* ws  = (float*)d_ws;

    ushort* am_bf = (ushort*)ws;                     // 4.19M bf16 each
    ushort* ad_bf = (ushort*)(ws + 2097152);
    ushort* kbf   = (ushort*)(ws + 4194304);
    ushort* vbf   = (ushort*)(ws + 6291456);
    ushort* qbf   = (ushort*)(ws + 8388608);
    ushort* xbf   = (ushort*)(ws + 12582912);
    ushort* wtbf  = (ushort*)(ws + 14680064);        // 786432 bf16
    ushort* wobf  = (ushort*)(ws + 15073280);        // 32768 bf16
    float*  part  = ws + 15089664;                   // 1048576 f32
    float*  zpart = ws + 16138240;                   // 16384 f32
    float*  pO    = ws + 16154624;                   // 1024*4096 = 4194304 f32
    float*  pl    = ws + 20348928;                   // 1024*64 = 65536 f32

    float* out_main = out;               // (4,2048,64)
    float* out_mem  = out + 524288;      // (4,8,64,64)
    float* out_z    = out + 655360;      // (4,8,64)

    pos_add_bf16_kernel<<<8192, 256, 0, stream>>>(inputs, xbf);
    wprep_kernel<<<224, 256, 0, stream>>>(attnk, wtbf, outk, wobf);
    qkv_mfma_kernel<<<dim3(64, 12), 256, 0, stream>>>(xbf, wtbf, kbf, vbf, qbf);
    amem_mfma_kernel<<<256, 256, 0, stream>>>(qbf, mem, zin, am_bf);
    delta_part_kernel<<<256, 256, 0, stream>>>(kbf, vbf, am_bf, part, zpart);
    delta_reduce_kernel<<<32, 256, 0, stream>>>(part, zpart, mem, zin, out_mem, out_z);
    flash6_kernel<<<1024, 256, 0, stream>>>(qbf, kbf, vbf, ad_bf, pO, pl);
    flash_combine_kernel<<<512, 256, 0, stream>>>(pO, pl, ad_bf);
    outproj_mfma_kernel<<<256, 256, 0, stream>>>(am_bf, ad_bf, wobf, beta, out_main);
}

// Round 11
// 182.419 us; speedup vs baseline: 1.0879x; 1.0879x over previous
//
#include <hip/hip_runtime.h>
#include <hip/hip_bf16.h>
#include <math.h>

// Problem constants (fixed by the harness)
#define BB 4
#define SEQ 2048
#define DIM 512
#define NH 8
#define HD 64

typedef __attribute__((ext_vector_type(8))) short short8;
typedef __attribute__((ext_vector_type(4))) float f32x4;
typedef __attribute__((ext_vector_type(2))) unsigned int u32x2;
typedef __attribute__((address_space(3))) const ushort lds_cushort;

static __device__ inline ushort f2bf(float f) {
    __hip_bfloat16 h = __float2bfloat16(f);
    union { __hip_bfloat16 h; ushort u; } cv;
    cv.h = h;
    return cv.u;
}
static __device__ inline float bf2f(ushort u) {
    return __uint_as_float((uint)u << 16);
}

#define GLOAD16(g, l)                                                          \
    __builtin_amdgcn_global_load_lds(                                          \
        (const __attribute__((address_space(1))) uint32_t*)(g),                \
        (__attribute__((address_space(3))) uint32_t*)(l), 16, 0, 0)

// hardware transpose read: 4 bf16 at 16-element (32B) stride from lane's address
static __device__ __forceinline__ u32x2 tr16_b64(lds_cushort* p) {
    u32x2 r;
    asm volatile("ds_read_b64_tr_b16 %0, %1" : "=v"(r) : "v"(p) : "memory");
    return r;
}

// ---------------- Kernel A: x_bf = bf16(inputs + sine positional encoding) --------
__global__ __launch_bounds__(256) void pos_add_bf16_kernel(const float* __restrict__ in,
                                                           ushort* __restrict__ xbf) {
    int idx = blockIdx.x * 256 + threadIdx.x;      // 2097152 pairs
    int p = idx & 255;
    int n = (idx >> 8) & 2047;
    float e = (float)(2 * p) * (1.0f / 512.0f);
    float ts = __expf(-6.907755278982137f * e);    // (1/1000)^e
    float arev = (float)n * (ts * 0.15915494309189535f);   // angle in revolutions
    float f = arev - floorf(arev);
    float s = __builtin_amdgcn_sinf(f);            // sin(2*pi*f)
    float c = __builtin_amdgcn_cosf(f);
    float2 v = *(const float2*)(in + (size_t)idx * 2);
    uint pack = (uint)f2bf(v.x + s) | ((uint)f2bf(v.y + c) << 16);
    ((uint*)xbf)[idx] = pack;
}

// ---------------- Kernel A2: weight prep (wconv + wout merged) --------------------
__global__ __launch_bounds__(256) void wprep_kernel(const float* __restrict__ w,
                                                    ushort* __restrict__ wt,
                                                    const float* __restrict__ wo,
                                                    ushort* __restrict__ wobf) {
    int bid = blockIdx.x;
    int t = threadIdx.x;
    if (bid < 96) {
        __shared__ float tile[64][129];
        int ib = bid & 7;    // 0..7   (i blocks of 64)
        int jb = bid >> 3;   // 0..11  (col blocks of 128)
        #pragma unroll
        for (int u = 0; u < 8; ++u) {
            int idx = u * 1024 + t * 4;
            int r = idx >> 7, j = idx & 127;
            float4 v = *(const float4*)(w + (size_t)(ib * 64 + r) * 1536 + jb * 128 + j);
            tile[r][j] = v.x; tile[r][j + 1] = v.y; tile[r][j + 2] = v.z; tile[r][j + 3] = v.w;
        }
        __syncthreads();
        int j = t >> 1;
        int rh = (t & 1) * 32;
        int jg = jb * 128 + j;                 // = h*192 + o*3 + c
        int h = jg / 192;
        int rem = jg - h * 192;
        int o = rem / 3;
        int c = rem - o * 3;
        int nrow = c * 512 + h * 64 + o;
        #pragma unroll
        for (int s8 = 0; s8 < 4; ++s8) {
            short8 pk;
            #pragma unroll
            for (int q = 0; q < 8; ++q) pk[q] = (short)f2bf(tile[rh + s8 * 8 + q][j]);
            *(short8*)(wt + (size_t)nrow * 512 + ib * 64 + rh + s8 * 8) = pk;
        }
    } else {
        int g = (bid - 96) * 256 + t;   // 32768 dst elems
        int o2 = g >> 9, k = g & 511;
        int h = k >> 6, i = k & 63;
        wobf[g] = f2bf(wo[(size_t)i * 512 + h * 64 + o2]);
    }
}

// ---------------- Kernel B: QKV GEMM, BK=64, coalesced LDS-transposed epilogue ----
__global__ __launch_bounds__(256) void qkv_mfma_kernel(const ushort* __restrict__ xbf,
                                                       const ushort* __restrict__ wt,
                                                       ushort* __restrict__ kbf,
                                                       ushort* __restrict__ vbf,
                                                       ushort* __restrict__ qbf) {
    __shared__ __align__(16) ushort smem[128 * 128];   // 32KB: As|Bs, reused as C
    ushort* As = smem;
    ushort* Bs = smem + 128 * 64;
    int t = threadIdx.x;
    int w = t >> 6, lane = t & 63, l15 = lane & 15, lg = lane >> 4;
    int wr = w >> 1, wc = w & 1;
    int m0 = blockIdx.x * 128;
    int by = blockIdx.y;
    int n0 = by * 128;
    int sw = l15 & 7;
    f32x4 acc[4][4] = {};

    int rowp[4], colp[4];
    #pragma unroll
    for (int p = 0; p < 4; ++p) {
        int ch = t + 256 * p;
        rowp[p] = ch >> 3;
        colp[p] = (((ch & 7) ^ (rowp[p] & 7))) * 8;
    }

    for (int k0 = 0; k0 < 512; k0 += 64) {
        __syncthreads();
        #pragma unroll
        for (int p = 0; p < 4; ++p)
            GLOAD16(xbf + (size_t)(m0 + rowp[p]) * 512 + k0 + colp[p], As + (t + 256 * p) * 8);
        #pragma unroll
        for (int p = 0; p < 4; ++p)
            GLOAD16(wt + (size_t)(n0 + rowp[p]) * 512 + k0 + colp[p], Bs + (t + 256 * p) * 8);
        __syncthreads();
        #pragma unroll
        for (int ks = 0; ks < 2; ++ks) {
            short8 af[4], bf[4];
            #pragma unroll
            for (int mi = 0; mi < 4; ++mi)
                af[mi] = *(const short8*)&As[(wr * 64 + mi * 16 + l15) * 64 + ((ks * 4 + lg) ^ sw) * 8];
            #pragma unroll
            for (int ni = 0; ni < 4; ++ni)
                bf[ni] = *(const short8*)&Bs[(wc * 64 + ni * 16 + l15) * 64 + ((ks * 4 + lg) ^ sw) * 8];
            #pragma unroll
            for (int mi = 0; mi < 4; ++mi)
                #pragma unroll
                for (int ni = 0; ni < 4; ++ni)
                    acc[mi][ni] = __builtin_amdgcn_mfma_f32_16x16x32_bf16(af[mi], bf[ni], acc[mi][ni], 0, 0, 0);
        }
    }

    // epilogue: stage C in LDS (chunk-XOR), then fully-coalesced 16B stores
    __syncthreads();
    #pragma unroll
    for (int mi = 0; mi < 4; ++mi)
        #pragma unroll
        for (int ni = 0; ni < 4; ++ni)
            #pragma unroll
            for (int r = 0; r < 4; ++r) {
                int row = wr * 64 + mi * 16 + lg * 4 + r;
                int col = wc * 64 + ni * 16 + l15;
                int cc = col >> 3;
                smem[row * 128 + ((cc ^ (row & 7)) * 8) + (col & 7)] = f2bf(acc[mi][ni][r]);
            }
    __syncthreads();
    ushort* dst = (by < 4) ? kbf : (by < 8) ? vbf : qbf;
    int cb = (by & 3) * 128;
    #pragma unroll
    for (int p = 0; p < 8; ++p) {
        int c = p * 256 + t;
        int row = c >> 4, cc = c & 15;
        short8 v = *(const short8*)&smem[row * 128 + ((cc ^ (row & 7)) * 8)];
        *(short8*)(dst + (size_t)(m0 + row) * 512 + cb + cc * 8) = v;
    }
}

// ---------------- Kernel C: A_mem via bf16 MFMA (den fused as B-row 64) -----------
__global__ __launch_bounds__(256) void amem_mfma_kernel(const ushort* __restrict__ qbf,
                                                        const float* __restrict__ mem,
                                                        const float* __restrict__ zin,
                                                        ushort* __restrict__ ambf) {
    int bid = blockIdx.x;               // 4*8*8 = 256
    int nt = bid & 7;
    int h = (bid >> 3) & 7;
    int b = bid >> 6;
    __shared__ __align__(16) ushort bt_s[80 * 64];
    int t = threadIdx.x;
    int w = t >> 6, lane = t & 63, l15 = lane & 15, lg = lane >> 4;

    {
        int d = t >> 2;
        int o0 = (t & 3) * 16;
        const float* msrc = mem + (size_t)(b * 8 + h) * 4096 + (size_t)d * 64 + o0;
        #pragma unroll
        for (int j = 0; j < 16; ++j) {
            int o = o0 + j;
            int c = (d >> 3) ^ (o & 7);
            bt_s[(o * 8 + c) * 8 + (d & 7)] = f2bf(msrc[j]);
        }
        if (t < 64) {
            bt_s[(64 * 8 + (t >> 3)) * 8 + (t & 7)] = f2bf(zin[(b * 8 + h) * 64 + t]);
        }
    }
    __syncthreads();

    int sw = l15 & 7;
    short8 bfr[5][2];
    #pragma unroll
    for (int n = 0; n < 5; ++n) {
        const ushort* br = &bt_s[(n * 16 + l15) * 64];
        bfr[n][0] = *(const short8*)&br[(lg ^ sw) * 8];
        bfr[n][1] = *(const short8*)&br[((4 + lg) ^ sw) * 8];
    }

    int rowbase = b * 2048 + nt * 256 + w * 64;
    f32x4 acc[4][5] = {};
    #pragma unroll
    for (int m = 0; m < 4; ++m) {
        const ushort* qrow = qbf + (size_t)(rowbase + m * 16 + l15) * 512 + h * 64;
        short8 q0 = *(const short8*)(qrow + lg * 8);
        short8 q1 = *(const short8*)(qrow + 32 + lg * 8);
        short8 a0, a1;
        #pragma unroll
        for (int j = 0; j < 8; ++j) {
            float f0 = bf2f((ushort)q0[j]);
            float f1 = bf2f((ushort)q1[j]);
            a0[j] = (short)f2bf(f0 > 0.f ? f0 + 1.f : __expf(f0));
            a1[j] = (short)f2bf(f1 > 0.f ? f1 + 1.f : __expf(f1));
        }
        #pragma unroll
        for (int n = 0; n < 5; ++n) {
            acc[m][n] = __builtin_amdgcn_mfma_f32_16x16x32_bf16(a0, bfr[n][0], acc[m][n], 0, 0, 0);
            acc[m][n] = __builtin_amdgcn_mfma_f32_16x16x32_bf16(a1, bfr[n][1], acc[m][n], 0, 0, 0);
        }
    }

    #pragma unroll
    for (int m = 0; m < 4; ++m) {
        float inv[4];
        #pragma unroll
        for (int r = 0; r < 4; ++r) {
            float d = __shfl(acc[m][4][r], (lane & 48));   // den from l15==0 lane
            inv[r] = 1.f / (d + 1e-8f);
        }
        #pragma unroll
        for (int r = 0; r < 4; ++r) {
            ushort* dst = ambf + (size_t)(rowbase + m * 16 + lg * 4 + r) * 512 + h * 64;
            #pragma unroll
            for (int n = 0; n < 4; ++n)
                dst[n * 16 + l15] = f2bf(acc[m][n][r] * inv[r]);
        }
    }
}

// ---------------- Kernel D1: delta partials (256 blocks) --------------------------
__global__ __launch_bounds__(256) void delta_part_kernel(const ushort* __restrict__ kbf,
                                                         const ushort* __restrict__ vbf,
                                                         const ushort* __restrict__ ambf,
                                                         float* __restrict__ part,
                                                         float* __restrict__ zpart) {
    int bid = blockIdx.x;      // chunk*32 + bh
    int bh = bid & 31;
    int chunk = bid >> 5;
    int h = bh & 7, b = bh >> 3;
    __shared__ __align__(16) float ke_s[2048];   // [32][64]
    __shared__ __align__(16) float vm_s[2048];
    int t = threadIdx.x;
    int tx = t & 15, ty = t >> 4;
    float acc[4][4] = {};
    float nz = 0.f;
    int nbase = chunk * 256;
    for (int n0 = 0; n0 < 256; n0 += 32) {
        {
            int nn = t >> 3, cc = (t & 7) * 8;
            size_t g = (size_t)(b * 2048 + nbase + n0 + nn) * 512 + h * 64 + cc;
            short8 k8 = *(const short8*)(kbf + g);
            short8 v8 = *(const short8*)(vbf + g);
            short8 a8 = *(const short8*)(ambf + g);
            #pragma unroll
            for (int j = 0; j < 8; ++j) {
                float kv = bf2f((ushort)k8[j]);
                ke_s[t * 8 + j] = kv > 0.f ? kv + 1.f : __expf(kv);
                vm_s[t * 8 + j] = bf2f((ushort)v8[j]) - bf2f((ushort)a8[j]);
            }
        }
        __syncthreads();
        #pragma unroll
        for (int nn = 0; nn < 32; ++nn) {
            float4 ka4 = *(const float4*)&ke_s[nn * 64 + ty * 4];
            float4 vv4 = *(const float4*)&vm_s[nn * 64 + tx * 4];
            float ka[4] = {ka4.x, ka4.y, ka4.z, ka4.w};
            float vv[4] = {vv4.x, vv4.y, vv4.z, vv4.w};
            #pragma unroll
            for (int i = 0; i < 4; ++i)
                #pragma unroll
                for (int j = 0; j < 4; ++j) acc[i][j] += ka[i] * vv[j];
        }
        if (t < 64) {
            #pragma unroll
            for (int nn = 0; nn < 32; ++nn) nz += ke_s[nn * 64 + t];
        }
        __syncthreads();
    }
    float* pdst = part + (size_t)bid * 4096;
    #pragma unroll
    for (int i = 0; i < 4; ++i)
        #pragma unroll
        for (int j = 0; j < 4; ++j)
            pdst[(ty * 4 + i) * 64 + tx * 4 + j] = acc[i][j];
    if (t < 64) zpart[bid * 64 + t] = nz;
}

// ---------------- Kernel D2: delta reduce -----------------------------------------
__global__ __launch_bounds__(256) void delta_reduce_kernel(const float* __restrict__ part,
                                                           const float* __restrict__ zpart,
                                                           const float* __restrict__ mem,
                                                           const float* __restrict__ zin,
                                                           float* __restrict__ out_mem,
                                                           float* __restrict__ out_z) {
    int bh = blockIdx.x;
    int t = threadIdx.x;
    #pragma unroll
    for (int q = 0; q < 4; ++q) {
        int e = t * 16 + q * 4;
        float4 acc = *(const float4*)(mem + (size_t)bh * 4096 + e);
        #pragma unroll
        for (int c = 0; c < 8; ++c) {
            float4 pv = *(const float4*)(part + (size_t)(c * 32 + bh) * 4096 + e);
            acc.x += pv.x; acc.y += pv.y; acc.z += pv.z; acc.w += pv.w;
        }
        *(float4*)(out_mem + (size_t)bh * 4096 + e) = acc;
    }
    if (t < 64) {
        float z = zin[bh * 64 + t];
        #pragma unroll
        for (int c = 0; c < 8; ++c) z += zpart[(c * 32 + bh) * 64 + t];
        out_z[bh * 64 + t] = z;
    }
}

// ---------------- Kernel E: flash5 (round-9 best) + s_setprio on MFMA clusters ----
__global__ __launch_bounds__(256, 2) void flash5_kernel(const ushort* __restrict__ qbf,
                                                        const ushort* __restrict__ kbf,
                                                        const ushort* __restrict__ vbf,
                                                        ushort* __restrict__ adbf) {
    int bid0 = blockIdx.x;
    int bid = (bid0 & 7) * 64 + (bid0 >> 3);       // 512 % 8 == 0: bijective XCD remap
    int i = bid & 15;
    int h = (bid >> 4) & 7;
    int b = bid >> 7;
    __shared__ __align__(16) ushort k_s[2][4096];  // [key 64][d 64], chunk-XOR swz
    __shared__ __align__(16) ushort v_s[2][4096];  // [dblk 4][n 64][d' 16], linear
    __shared__ __align__(16) ushort p_s[4][1024];  // per-wave P^T [k 64][q 16]
    int t = threadIdx.x;
    int w = t >> 6, lane = t & 63, l15 = lane & 15, lg = lane >> 4;
    const int rA = i, rB = 31 - i;
    const int sw = l15 & 7;
    const float C = 0.06375875f;   // (1/sqrt(512)) * log2(e)

    const ushort* qbase = qbf + (size_t)(b * 2048) * 512 + h * 64 + lg * 8;
    short8 qfA[2], qfB[2];
    #pragma unroll
    for (int c = 0; c < 2; ++c) {
        short8 ra = *(const short8*)(qbase + (size_t)(rA * 64 + w * 16 + l15) * 512 + c * 32);
        short8 rb = *(const short8*)(qbase + (size_t)(rB * 64 + w * 16 + l15) * 512 + c * 32);
        #pragma unroll
        for (int j = 0; j < 8; ++j) {
            qfA[c][j] = (short)f2bf(bf2f((ushort)ra[j]) * C);
            qfB[c][j] = (short)f2bf(bf2f((ushort)rb[j]) * C);
        }
    }
    f32x4 oA[4] = {}, oB[4] = {};
    f32x4 lA = {0.f, 0.f, 0.f, 0.f}, lB = {0.f, 0.f, 0.f, 0.f};

    int ch0 = t, ch1 = t + 256;
    int krow0 = ch0 >> 3, ksc0 = (ch0 & 7) ^ (krow0 & 7);
    int krow1 = ch1 >> 3, ksc1 = (ch1 & 7) ^ (krow1 & 7);
    int vd0 = ch0 >> 7, vn0 = (ch0 >> 1) & 63, vh0 = ch0 & 1;
    int vd1 = ch1 >> 7, vn1 = (ch1 >> 1) & 63, vh1 = ch1 & 1;
    const ushort* kbase = kbf + (size_t)(b * 2048) * 512 + h * 64;
    const ushort* vbase = vbf + (size_t)(b * 2048) * 512 + h * 64;
    ushort* pw = &p_s[w][0];

    short8 ones;
    #pragma unroll
    for (int j = 0; j < 8; ++j) ones[j] = (short)0x3F80;   // bf16 1.0

    short8 kf[4][2], vf[4][2];

    auto STAGE = [&](int buf, int kt) {
        GLOAD16(kbase + (size_t)(kt * 64 + krow0) * 512 + ksc0 * 8, &k_s[buf][ch0 * 8]);
        GLOAD16(kbase + (size_t)(kt * 64 + krow1) * 512 + ksc1 * 8, &k_s[buf][ch1 * 8]);
        GLOAD16(vbase + (size_t)(kt * 64 + vn0) * 512 + vd0 * 16 + vh0 * 8, &v_s[buf][ch0 * 8]);
        GLOAD16(vbase + (size_t)(kt * 64 + vn1) * 512 + vd1 * 16 + vh1 * 8, &v_s[buf][ch1 * 8]);
    };

    auto proc = [&](const short8* qf, f32x4* oo, f32x4& ll, int rt, int kt) {
        f32x4 s[4];
        __builtin_amdgcn_s_setprio(1);
        #pragma unroll
        for (int t4 = 0; t4 < 4; ++t4) {
            f32x4 z = {0.f, 0.f, 0.f, 0.f};
            z = __builtin_amdgcn_mfma_f32_16x16x32_bf16(qf[0], kf[t4][0], z, 0, 0, 0);
            z = __builtin_amdgcn_mfma_f32_16x16x32_bf16(qf[1], kf[t4][1], z, 0, 0, 0);
            s[t4] = z;
        }
        __builtin_amdgcn_s_setprio(0);
        if (kt == rt) {
            #pragma unroll
            for (int t4 = 0; t4 < 4; ++t4) {
                int colb = t4 * 16 + l15;
                int rowb = w * 16 + lg * 4;
                #pragma unroll
                for (int r = 0; r < 4; ++r)
                    if (colb > rowb + r) s[t4][r] = -1e30f;
            }
        }
        #pragma unroll
        for (int t4 = 0; t4 < 4; ++t4) {
            union { ushort u[4]; u32x2 d; } pk;
            #pragma unroll
            for (int r = 0; r < 4; ++r)
                pk.u[r] = f2bf(__builtin_amdgcn_exp2f(s[t4][r]));
            *(u32x2*)&pw[(t4 * 16 + l15) * 16 + lg * 4] = pk.d;
        }
        u32x2 praw0, praw1, praw2, praw3;
        {
            lds_cushort* pb = (lds_cushort*)&pw[l15];
            praw0 = tr16_b64(pb + (lg * 8 + 0) * 16);
            praw1 = tr16_b64(pb + (lg * 8 + 4) * 16);
            praw2 = tr16_b64(pb + (32 + lg * 8 + 0) * 16);
            praw3 = tr16_b64(pb + (32 + lg * 8 + 4) * 16);
        }
        asm volatile("s_waitcnt lgkmcnt(0)" ::: "memory");
        __builtin_amdgcn_sched_barrier(0);
        union { u32x2 d[2]; short8 s8; } up0, up1;
        up0.d[0] = praw0; up0.d[1] = praw1;
        up1.d[0] = praw2; up1.d[1] = praw3;
        short8 pf0 = up0.s8, pf1 = up1.s8;
        __builtin_amdgcn_s_setprio(1);
        ll = __builtin_amdgcn_mfma_f32_16x16x32_bf16(pf0, ones, ll, 0, 0, 0);
        ll = __builtin_amdgcn_mfma_f32_16x16x32_bf16(pf1, ones, ll, 0, 0, 0);
        #pragma unroll
        for (int dt = 0; dt < 4; ++dt) {
            oo[dt] = __builtin_amdgcn_mfma_f32_16x16x32_bf16(pf0, vf[dt][0], oo[dt], 0, 0, 0);
            oo[dt] = __builtin_amdgcn_mfma_f32_16x16x32_bf16(pf1, vf[dt][1], oo[dt], 0, 0, 0);
        }
        __builtin_amdgcn_s_setprio(0);
    };

    STAGE(0, 0);
    for (int kt = 0; kt <= rB; ++kt) {
        int cur = kt & 1;
        __builtin_amdgcn_s_barrier();
        if (kt < rB) {
            STAGE(cur ^ 1, kt + 1);
            asm volatile("s_waitcnt vmcnt(4)" ::: "memory");
        } else {
            asm volatile("s_waitcnt vmcnt(0)" ::: "memory");
        }
        __builtin_amdgcn_s_barrier();
        #pragma unroll
        for (int t4 = 0; t4 < 4; ++t4) {
            const ushort* kr = &k_s[cur][(t4 * 16 + l15) * 64];
            kf[t4][0] = *(const short8*)&kr[(lg ^ sw) * 8];
            kf[t4][1] = *(const short8*)&kr[((4 + lg) ^ sw) * 8];
        }
        u32x2 vraw[4][4];
        #pragma unroll
        for (int dt = 0; dt < 4; ++dt) {
            lds_cushort* vb = (lds_cushort*)&v_s[cur][dt * 1024 + l15];
            vraw[dt][0] = tr16_b64(vb + (lg * 8 + 0) * 16);
            vraw[dt][1] = tr16_b64(vb + (lg * 8 + 4) * 16);
            vraw[dt][2] = tr16_b64(vb + (32 + lg * 8 + 0) * 16);
            vraw[dt][3] = tr16_b64(vb + (32 + lg * 8 + 4) * 16);
        }
        asm volatile("s_waitcnt lgkmcnt(0)" ::: "memory");
        __builtin_amdgcn_sched_barrier(0);
        #pragma unroll
        for (int dt = 0; dt < 4; ++dt) {
            union { u32x2 d[2]; short8 s8; } u0, u1;
            u0.d[0] = vraw[dt][0]; u0.d[1] = vraw[dt][1];
            u1.d[0] = vraw[dt][2]; u1.d[1] = vraw[dt][3];
            vf[dt][0] = u0.s8;
            vf[dt][1] = u1.s8;
        }
        proc(qfB, oB, lB, rB, kt);
        if (kt <= rA) proc(qfA, oA, lA, rA, kt);
    }

    auto fin = [&](f32x4* oo, f32x4& ll, int rt) {
        #pragma unroll
        for (int r = 0; r < 4; ++r) {
            float inv = 1.f / ll[r];
            ushort* dst = adbf + (size_t)(b * 2048 + rt * 64 + w * 16 + lg * 4 + r) * 512 + h * 64;
            #pragma unroll
            for (int dt = 0; dt < 4; ++dt)
                dst[dt * 16 + l15] = f2bf(oo[dt][r] * inv);
        }
    };
    fin(oA, lA, rA);
    fin(oB, lB, rB);
}

// ---------------- Kernel F: gated mix + output projection, 256 blocks -------------
__global__ __launch_bounds__(256) void outproj_mfma_kernel(const ushort* __restrict__ ambf,
                                                           const ushort* __restrict__ adbf,
                                                           const ushort* __restrict__ wobf,
                                                           const float* __restrict__ beta,
                                                           float* __restrict__ out) {
    __shared__ __align__(16) ushort W_s[64 * 512];   // 64KB, row o2, swizzled chunks
    __shared__ __align__(16) ushort A_s[32 * 64];    // 4KB, row m, swizzled chunks
    int t = threadIdx.x;
    int w = t >> 6, lane = t & 63, l15 = lane & 15, lg = lane >> 4;
    int msub = w & 1, nh = w >> 1;
    int m0 = blockIdx.x * 32;
    float g = 1.f / (1.f + __expf(-beta[0]));
    float gi = 1.f - g;

    #pragma unroll
    for (int p = 0; p < 16; ++p) {
        int ch = p * 256 + t;
        int row = ch >> 6, c = ch & 63;
        int cs = c ^ (row & 7);
        GLOAD16(wobf + (size_t)row * 512 + cs * 8, W_s + ch * 8);
    }

    int ar = t >> 3, ac = t & 7;   // 32 rows x 8 chunks
    int sw = l15 & 7;
    f32x4 acc[2] = {};

    for (int ks = 0; ks < 8; ++ks) {
        size_t gofs = (size_t)(m0 + ar) * 512 + ks * 64 + ac * 8;
        short8 a8 = *(const short8*)(ambf + gofs);
        short8 d8 = *(const short8*)(adbf + gofs);
        short8 x0;
        #pragma unroll
        for (int j = 0; j < 8; ++j)
            x0[j] = (short)f2bf(g * bf2f((ushort)a8[j]) + gi * bf2f((ushort)d8[j]));
        if (ks) __syncthreads();
        *(short8*)&A_s[(ar * 8 + (ac ^ (ar & 7))) * 8] = x0;
        __syncthreads();

        const ushort* arow = &A_s[(msub * 16 + l15) * 64];
        short8 af0 = *(const short8*)&arow[(lg ^ sw) * 8];
        short8 af1 = *(const short8*)&arow[((4 + lg) ^ sw) * 8];
        #pragma unroll
        for (int ni = 0; ni < 2; ++ni) {
            const ushort* wrow = &W_s[(nh * 32 + ni * 16 + l15) * 512];
            short8 bf0 = *(const short8*)&wrow[(ks * 8 + (lg ^ sw)) * 8];
            short8 bf1 = *(const short8*)&wrow[(ks * 8 + ((4 + lg) ^ sw)) * 8];
            acc[ni] = __builtin_amdgcn_mfma_f32_16x16x32_bf16(af0, bf0, acc[ni], 0, 0, 0);
            acc[ni] = __builtin_amdgcn_mfma_f32_16x16x32_bf16(af1, bf1, acc[ni], 0, 0, 0);
        }
    }

    #pragma unroll
    for (int ni = 0; ni < 2; ++ni)
        #pragma unroll
        for (int r = 0; r < 4; ++r)
            out[(size_t)(m0 + msub * 16 + lg * 4 + r) * 64 + nh * 32 + ni * 16 + l15] = acc[ni][r];
}

// ---------------- launcher --------------------------------------------------------
extern "C" void kernel_launch(void* const* d_in, const int* in_sizes, int n_in,
                              void* d_out, int out_size, void* d_ws, size_t ws_size,
                              hipStream_t stream) {
    const float* inputs = (const float*)d_in[0];
    const float* mem    = (const float*)d_in[1];
    const float* zin    = (const float*)d_in[2];
    const float* attnk  = (const float*)d_in[3];
    const float* outk   = (const float*)d_in[4];
    const float* beta   = (const float*)d_in[5];
    float* out = (float*)d_out;
    float* ws  = (float*)d_ws;

    ushort* am_bf = (ushort*)ws;                     // 4.19M bf16 each
    ushort* ad_bf = (ushort*)(ws + 2097152);
    ushort* kbf   = (ushort*)(ws + 4194304);
    ushort* vbf   = (ushort*)(ws + 6291456);
    ushort* qbf   = (ushort*)(ws + 8388608);
    ushort* xbf   = (ushort*)(ws + 12582912);
    ushort* wtbf  = (ushort*)(ws + 14680064);        // 786432 bf16
    ushort* wobf  = (ushort*)(ws + 15073280);        // 32768 bf16
    float*  part  = ws + 15089664;                   // 1048576 f32
    float*  zpart = ws + 16138240;                   // 16384 f32

    float* out_main = out;               // (4,2048,64)
    float* out_mem  = out + 524288;      // (4,8,64,64)
    float* out_z    = out + 655360;      // (4,8,64)

    pos_add_bf16_kernel<<<8192, 256, 0, stream>>>(inputs, xbf);
    wprep_kernel<<<224, 256, 0, stream>>>(attnk, wtbf, outk, wobf);
    qkv_mfma_kernel<<<dim3(64, 12), 256, 0, stream>>>(xbf, wtbf, kbf, vbf, qbf);
    amem_mfma_kernel<<<256, 256, 0, stream>>>(qbf, mem, zin, am_bf);
    delta_part_kernel<<<256, 256, 0, stream>>>(kbf, vbf, am_bf, part, zpart);
    delta_reduce_kernel<<<32, 256, 0, stream>>>(part, zpart, mem, zin, out_mem, out_z);
    flash5_kernel<<<512, 256, 0, stream>>>(qbf, kbf, vbf, ad_bf);
    outproj_mfma_kernel<<<256, 256, 0, stream>>>(am_bf, ad_bf, wobf, beta, out_main);
}